// Round 8
// baseline (498.147 us; speedup 1.0000x reference)
//
#include <hip/hip_runtime.h>
#include <stdint.h>

#define BATCH 128
#define SEQL  512
#define FDIM  768
#define CTAGS 52
#define START_IDX 50
#define STOP_IDX  51
#define NEG_INF (-3.0e38f)

#define WTP_LD 56          // padded WT row (224 B, 16B-aligned)
#define CH    64           // chunk = 64 time steps
#define NCH   (SEQL / CH)  // 8 chunks
#define NC    20           // cols per gemm wave (overlapping: 0-19,16-35,32-51)

// ---------------------------------------------------------------------------
// K0: transpose W [52][768] -> WTP [768][56] (padded, zeros in cols 52-55).
// ---------------------------------------------------------------------------
__global__ __launch_bounds__(256) void wtrans(
    const float* __restrict__ W, float* __restrict__ WTP)
{
    int idx = blockIdx.x * 256 + threadIdx.x;
    if (idx < FDIM * WTP_LD) {
        int k = idx / WTP_LD;
        int c = idx - k * WTP_LD;
        WTP[idx] = (c < CTAGS) ? W[(size_t)c * FDIM + k] : 0.f;
    }
}

// ---------------------------------------------------------------------------
// K1 (fused): per-batch block, 4 waves.
//   wave 0  : serial Viterbi scan (R7 structure: LDS state broadcast,
//             13 named T-row quads, max3 tree, s_hist store).
//   waves1-3: emission GEMM for the NEXT chunk, written straight to LDS.
//             lane=row(=time step), 20 cols/wave (c0=0/16/32, 16B-aligned,
//             overlap cols double-written with identical values).
//             W via scalar s_load path; F via per-lane dwordx4 (L1-resident
//             4KB window shared by the 3 waves). Emissions never hit global.
//   One __syncthreads per chunk (double-buffered ebuf).
// ---------------------------------------------------------------------------
__global__ __launch_bounds__(256) void fused_scan(
    const float* __restrict__ F, const float* __restrict__ WTP,
    const float* __restrict__ bias, const int* __restrict__ masks,
    const float* __restrict__ T, float* __restrict__ s_hist,
    float* __restrict__ out, int* __restrict__ btag)
{
    const int b    = blockIdx.x;
    const int tid  = threadIdx.x;
    const int lane = tid & 63;
    const int wid  = __builtin_amdgcn_readfirstlane(tid >> 6);

    __shared__ float ebuf[2][CH * CTAGS];          // 2 x 13312 B
    __shared__ int   ml[SEQL];                     // 2 KB
    __shared__ __align__(16) float st[64];         // state vector (52 used)

    const int toc = (lane < CTAGS) ? lane : (CTAGS - 1);

    // ---- scan-wave persistent registers (harmless for gemm waves) ----
    const float4* Tq = (const float4*)(T + (size_t)toc * CTAGS);
    float4 tr0, tr1, tr2, tr3, tr4, tr5, tr6, tr7, tr8, tr9, tr10, tr11, tr12;
    float tstop = 0.f, cur = 0.f;
    float* sb = s_hist + (size_t)b * SEQL * CTAGS;

    // ---- gemm-wave setup ----
    const int c0 = (wid > 0) ? (wid - 1) * 16 : 0;   // uniform per wave

    if (wid == 0) {
        // stage masks, init state
#pragma unroll
        for (int j = 0; j < 8; ++j)
            ml[lane + 64 * j] = masks[(size_t)b * SEQL + lane + 64 * j];
        st[lane] = (lane == START_IDX) ? 0.f : -10000.f;
        cur = (lane == START_IDX) ? 0.f : -10000.f;
        tr0 = Tq[0];  tr1 = Tq[1];  tr2 = Tq[2];   tr3 = Tq[3];
        tr4 = Tq[4];  tr5 = Tq[5];  tr6 = Tq[6];   tr7 = Tq[7];
        tr8 = Tq[8];  tr9 = Tq[9];  tr10 = Tq[10]; tr11 = Tq[11];
        tr12 = Tq[12];
        tstop = T[STOP_IDX * CTAGS + toc];
    } else {
        // prologue: compute chunk 0 into ebuf[0]
        const float* frow = F + ((size_t)b * SEQL + 0 * CH + lane) * FDIM;
        float acc[NC];
#pragma unroll
        for (int j = 0; j < NC; ++j) acc[j] = bias[c0 + j];
        for (int kq = 0; kq < FDIM / 4; ++kq) {
            float4 f4 = *(const float4*)(frow + kq * 4);
            const float* w0 = WTP + (size_t)(4 * kq + 0) * WTP_LD + c0;
            const float* w1 = WTP + (size_t)(4 * kq + 1) * WTP_LD + c0;
            const float* w2 = WTP + (size_t)(4 * kq + 2) * WTP_LD + c0;
            const float* w3 = WTP + (size_t)(4 * kq + 3) * WTP_LD + c0;
#pragma unroll
            for (int j = 0; j < NC; ++j) {
                acc[j] = fmaf(f4.x, w0[j], acc[j]);
                acc[j] = fmaf(f4.y, w1[j], acc[j]);
                acc[j] = fmaf(f4.z, w2[j], acc[j]);
                acc[j] = fmaf(f4.w, w3[j], acc[j]);
            }
        }
#pragma unroll
        for (int j = 0; j < NC; ++j) {
            int c = c0 + j;
            if (c < CTAGS) ebuf[0][lane * CTAGS + c] = acc[j];
        }
    }
    __syncthreads();

    int cb = 0;
    for (int ch = 0; ch < NCH; ++ch) {
        if (wid != 0) {
            // ---------------- gemm waves: chunk ch+1 -> ebuf[cb^1] --------
            if (ch + 1 < NCH) {
                const float* frow =
                    F + ((size_t)b * SEQL + (ch + 1) * CH + lane) * FDIM;
                float acc[NC];
#pragma unroll
                for (int j = 0; j < NC; ++j) acc[j] = bias[c0 + j];
                for (int kq = 0; kq < FDIM / 4; ++kq) {
                    float4 f4 = *(const float4*)(frow + kq * 4);
                    const float* w0 = WTP + (size_t)(4 * kq + 0) * WTP_LD + c0;
                    const float* w1 = WTP + (size_t)(4 * kq + 1) * WTP_LD + c0;
                    const float* w2 = WTP + (size_t)(4 * kq + 2) * WTP_LD + c0;
                    const float* w3 = WTP + (size_t)(4 * kq + 3) * WTP_LD + c0;
#pragma unroll
                    for (int j = 0; j < NC; ++j) {
                        acc[j] = fmaf(f4.x, w0[j], acc[j]);
                        acc[j] = fmaf(f4.y, w1[j], acc[j]);
                        acc[j] = fmaf(f4.z, w2[j], acc[j]);
                        acc[j] = fmaf(f4.w, w3[j], acc[j]);
                    }
                }
                const int nb = cb ^ 1;
#pragma unroll
                for (int j = 0; j < NC; ++j) {
                    int c = c0 + j;
                    if (c < CTAGS) ebuf[nb][lane * CTAGS + c] = acc[j];
                }
            }
        } else {
            // ---------------- scan wave: chunk ch from ebuf[cb] -----------
            for (int s = 0; s < CH; ++s) {
                const int t = ch * CH + s;

                // issue e/m early; consumed ~300+ cycles later
                float e = ebuf[cb][s * CTAGS + toc];
                int   m = ml[t];

                // store pre-update state
                if (lane < CTAGS) sb[(size_t)t * CTAGS + lane] = cur;

                // broadcast state via uniform-address LDS quad reads
                const float4 s0q  = *(const float4*)&st[0];
                const float4 s1q  = *(const float4*)&st[4];
                const float4 s2q  = *(const float4*)&st[8];
                const float4 s3q  = *(const float4*)&st[12];
                const float4 s4q  = *(const float4*)&st[16];
                const float4 s5q  = *(const float4*)&st[20];
                const float4 s6q  = *(const float4*)&st[24];
                const float4 s7q  = *(const float4*)&st[28];
                const float4 s8q  = *(const float4*)&st[32];
                const float4 s9q  = *(const float4*)&st[36];
                const float4 s10q = *(const float4*)&st[40];
                const float4 s11q = *(const float4*)&st[44];
                const float4 s12q = *(const float4*)&st[48];

                float a[CTAGS];
#define ADQ(q, sq, trq)                                                      \
                a[4*q+0] = sq.x + trq.x;  a[4*q+1] = sq.y + trq.y;           \
                a[4*q+2] = sq.z + trq.z;  a[4*q+3] = sq.w + trq.w;
                ADQ(0, s0q, tr0)   ADQ(1, s1q, tr1)   ADQ(2, s2q, tr2)
                ADQ(3, s3q, tr3)   ADQ(4, s4q, tr4)   ADQ(5, s5q, tr5)
                ADQ(6, s6q, tr6)   ADQ(7, s7q, tr7)   ADQ(8, s8q, tr8)
                ADQ(9, s9q, tr9)   ADQ(10, s10q, tr10) ADQ(11, s11q, tr11)
                ADQ(12, s12q, tr12)
#undef ADQ

                float l1[17];
#pragma unroll
                for (int i = 0; i < 17; ++i)
                    l1[i] = fmaxf(fmaxf(a[3 * i], a[3 * i + 1]), a[3 * i + 2]);
                float l2[6];
#pragma unroll
                for (int i = 0; i < 5; ++i)
                    l2[i] = fmaxf(fmaxf(l1[3 * i], l1[3 * i + 1]), l1[3 * i + 2]);
                l2[5] = fmaxf(fmaxf(l1[15], l1[16]), a[51]);
                const float mx = fmaxf(fmaxf(fmaxf(l2[0], l2[1]), l2[2]),
                                       fmaxf(fmaxf(l2[3], l2[4]), l2[5]));

                cur = m ? (mx + e) : cur;

                // publish new state (single-wave in-order LDS)
                if (lane < CTAGS) st[lane] = cur;
            }
        }
        __syncthreads();
        cb ^= 1;
    }

    if (wid == 0) {
        // final scores + wave argmax (first-index tiebreak)
        float v   = (lane < CTAGS) ? (cur + tstop) : NEG_INF;
        int  bidx = lane;
#pragma unroll
        for (int s = 1; s < 64; s <<= 1) {
            float ov = __shfl_xor(v, s);
            int   oi = __shfl_xor(bidx, s);
            if (ov > v || (ov == v && oi < bidx)) { v = ov; bidx = oi; }
        }
        if (lane == 0) { out[b] = v; btag[b] = bidx; }
    }
}

// ---------------------------------------------------------------------------
// K3: backpointers, parallel over (b,t). (unchanged, known-good)
// ---------------------------------------------------------------------------
#define PPW 16

__global__ __launch_bounds__(256) void bp_compute(
    const float* __restrict__ s_hist, const float* __restrict__ T,
    unsigned char* __restrict__ bp)
{
    const int lane = threadIdx.x & 63;
    const int wv   = __builtin_amdgcn_readfirstlane(threadIdx.x >> 6);
    const int toc  = (lane < CTAGS) ? lane : (CTAGS - 1);
    const int w    = blockIdx.x * 4 + wv;

    float Trow[CTAGS];
#pragma unroll
    for (int f = 0; f < CTAGS; ++f) Trow[f] = T[toc * CTAGS + f];

    for (int i = 0; i < PPW; ++i) {
        const int p = w * PPW + i;            // p = b*SEQL + t
        const float* sp = s_hist + (size_t)p * CTAGS;

        float a[CTAGS];
#pragma unroll
        for (int q = 0; q < 13; ++q) {
            float4 sv = *(const float4*)(sp + q * 4);
            a[q * 4 + 0] = sv.x + Trow[q * 4 + 0];
            a[q * 4 + 1] = sv.y + Trow[q * 4 + 1];
            a[q * 4 + 2] = sv.z + Trow[q * 4 + 2];
            a[q * 4 + 3] = sv.w + Trow[q * 4 + 3];
        }

        float l1[17];
#pragma unroll
        for (int j = 0; j < 17; ++j)
            l1[j] = fmaxf(fmaxf(a[3 * j], a[3 * j + 1]), a[3 * j + 2]);
        float l2[6];
#pragma unroll
        for (int j = 0; j < 5; ++j)
            l2[j] = fmaxf(fmaxf(l1[3 * j], l1[3 * j + 1]), l1[3 * j + 2]);
        l2[5] = fmaxf(fmaxf(l1[15], l1[16]), a[51]);
        const float m = fmaxf(fmaxf(fmaxf(l2[0], l2[1]), l2[2]),
                              fmaxf(fmaxf(l2[3], l2[4]), l2[5]));

        int c1[18];
#pragma unroll
        for (int j = 0; j < 17; ++j) {
            int x = (a[3 * j]     == m) ? (3 * j)     : 63;
            int y = (a[3 * j + 1] == m) ? (3 * j + 1) : 63;
            int z = (a[3 * j + 2] == m) ? (3 * j + 2) : 63;
            c1[j] = min(min(x, y), z);
        }
        c1[17] = (a[51] == m) ? 51 : 63;
        int c2[6];
#pragma unroll
        for (int j = 0; j < 6; ++j)
            c2[j] = min(min(c1[3 * j], c1[3 * j + 1]), c1[3 * j + 2]);
        const int idx = min(min(min(c2[0], c2[1]), c2[2]),
                            min(min(c2[3], c2[4]), c2[5]));

        if (lane < CTAGS)
            bp[(size_t)p * CTAGS + lane] = (unsigned char)idx;
    }
}

// ---------------------------------------------------------------------------
// K4: backtrack (unchanged, known-good).
// ---------------------------------------------------------------------------
__global__ __launch_bounds__(64) void viterbi_bt(
    const unsigned char* __restrict__ bp, const int* __restrict__ masks,
    const int* __restrict__ btag, float* __restrict__ out)
{
    const int b   = blockIdx.x;
    const int tid = threadIdx.x;

    __shared__ __align__(16) unsigned char bpl[SEQL * CTAGS];
    __shared__ int ml[SEQL];
    __shared__ unsigned char pathb[SEQL];

    const uint4* src = (const uint4*)(bp + (size_t)b * SEQL * CTAGS);
    for (int i = tid; i < SEQL * CTAGS / 16; i += 64)
        ((uint4*)bpl)[i] = src[i];
    for (int i = tid; i < SEQL; i += 64) ml[i] = masks[(size_t)b * SEQL + i];
    __syncthreads();

    int c = btag[b];
    if (tid == 0) pathb[SEQL - 1] = (unsigned char)c;
    for (int i = SEQL - 2; i >= 0; --i) {
        int nxt = bpl[(i + 1) * CTAGS + c];
        c = ml[i] ? nxt : c;
        if (tid == 0) pathb[i] = (unsigned char)c;
    }
    __syncthreads();

    float* po = out + BATCH + (size_t)b * SEQL;
#pragma unroll
    for (int i = 0; i < 8; ++i)
        po[i * 64 + tid] = (float)pathb[i * 64 + tid];
}

// ---------------------------------------------------------------------------
extern "C" void kernel_launch(void* const* d_in, const int* in_sizes, int n_in,
                              void* d_out, int out_size, void* d_ws, size_t ws_size,
                              hipStream_t stream)
{
    const float* features = (const float*)d_in[0];
    const int*   masks    = (const int*)d_in[1];
    const float* W        = (const float*)d_in[2];
    const float* bias     = (const float*)d_in[3];
    const float* T        = (const float*)d_in[4];

    float* out = (float*)d_out;

    // ws layout: s_hist (13.63 MB) | bp (3.41 MB) | btag
    // WTP (172 KB) aliases the bp region: written before fused_scan, dead
    // before bp_compute overwrites it (stream-ordered).
    const size_t sh_bytes = (size_t)BATCH * SEQL * CTAGS * sizeof(float);
    const size_t bp_bytes = (size_t)BATCH * SEQL * CTAGS;
    float*         s_hist = (float*)d_ws;
    unsigned char* bpws   = (unsigned char*)d_ws + sh_bytes;
    float*         WTP    = (float*)bpws;
    int*           btag   = (int*)((unsigned char*)d_ws + sh_bytes + bp_bytes);

    wtrans<<<(FDIM * WTP_LD + 255) / 256, 256, 0, stream>>>(W, WTP);
    fused_scan<<<BATCH, 256, 0, stream>>>(features, WTP, bias, masks, T,
                                          s_hist, out, btag);
    bp_compute<<<BATCH * SEQL / (4 * PPW), 256, 0, stream>>>(s_hist, T, bpws);
    viterbi_bt<<<BATCH, 64, 0, stream>>>(bpws, masks, btag, out);
}